// Round 8
// baseline (153.650 us; speedup 1.0000x reference)
//
#include <hip/hip_runtime.h>
#include <hip/hip_bf16.h>

typedef short bf16x8 __attribute__((ext_vector_type(8)));
typedef short s16x4  __attribute__((ext_vector_type(4)));
typedef float f32x4  __attribute__((ext_vector_type(4)));

#define NB 8
#define NC 512
#define NS 1024
#define NH 8
#define DH 64
#define GN_GROUPS 32
#define GN_EPS 1e-5f

#if __has_builtin(__builtin_amdgcn_exp2f)
#define EXP2(x) __builtin_amdgcn_exp2f(x)
#else
#define EXP2(x) __expf((x) * 0.69314718056f)
#endif

static __device__ __forceinline__ short f2bf(float f) {
  union { __hip_bfloat16 h; short s; } u;
  u.h = __float2bfloat16(f);
  return u.s;
}

// round-to-nearest (ties up) bf16 pair pack: 2 adds + 1 v_perm_b32
static __device__ __forceinline__ int pack2bf_fast(float a, float b) {
  unsigned ua = __float_as_uint(a) + 0x8000u;
  unsigned ub = __float_as_uint(b) + 0x8000u;
  return (int)__builtin_amdgcn_perm(ub, ua, 0x07060302u);  // a in low 16 bits
}

static __device__ __forceinline__ void async_lds16(const void* g, void* l) {
  __builtin_amdgcn_global_load_lds((__attribute__((address_space(1))) void*)(g),
                                   (__attribute__((address_space(3))) void*)(l),
                                   16, 0, 0);
}

#define MFMA16(a, b, c) __builtin_amdgcn_mfma_f32_16x16x32_bf16((a), (b), (c), 0, 0, 0)

// ---------------- kernel 1: weight convert + groupnorm stats (one launch) ----------------
__global__ __launch_bounds__(256) void prep(const float* __restrict__ x,
                                            float* __restrict__ stats,
                                            const float4* __restrict__ Wq,
                                            const float4* __restrict__ Wk,
                                            const float4* __restrict__ Wv,
                                            const float4* __restrict__ Wo,
                                            s16x4* __restrict__ oq, s16x4* __restrict__ ok,
                                            s16x4* __restrict__ ov, s16x4* __restrict__ oo,
                                            float qscale) {
  if (blockIdx.x < 256) {  // groupnorm stats: block per (b,g)
    int bg = blockIdx.x;
    const float4* p = (const float4*)(x + (size_t)bg * 16384);
    float s = 0.f, s2 = 0.f;
    for (int i = threadIdx.x; i < 4096; i += 256) {
      float4 v = p[i];
      s  += v.x + v.y + v.z + v.w;
      s2 += v.x * v.x + v.y * v.y + v.z * v.z + v.w * v.w;
    }
    for (int off = 32; off > 0; off >>= 1) {
      s  += __shfl_down(s, off, 64);
      s2 += __shfl_down(s2, off, 64);
    }
    __shared__ float red[8];
    int w = threadIdx.x >> 6;
    if ((threadIdx.x & 63) == 0) { red[w * 2] = s; red[w * 2 + 1] = s2; }
    __syncthreads();
    if (threadIdx.x == 0) {
      float S = 0.f, S2 = 0.f;
      for (int i = 0; i < 4; i++) { S += red[i * 2]; S2 += red[i * 2 + 1]; }
      float mu  = S / 16384.f;
      float var = S2 / 16384.f - mu * mu;
      stats[bg * 2]     = mu;
      stats[bg * 2 + 1] = rsqrtf(var + GN_EPS);
    }
  } else {  // weight fp32 -> bf16
    int idx = blockIdx.x - 256;
    int sel = idx >> 8;
    int i = (idx & 255) * 256 + threadIdx.x;
    const float4* src = (sel == 0) ? Wq : (sel == 1) ? Wk : (sel == 2) ? Wv : Wo;
    s16x4* dst        = (sel == 0) ? oq : (sel == 1) ? ok : (sel == 2) ? ov : oo;
    float scale = (sel == 0) ? qscale : 1.0f;
    float4 f = src[i];
    s16x4 o;
    o[0] = f2bf(f.x * scale); o[1] = f2bf(f.y * scale);
    o[2] = f2bf(f.z * scale); o[3] = f2bf(f.w * scale);
    dst[i] = o;
  }
}

// ---------------- kernel 2: transpose + groupnorm apply ----------------
__global__ __launch_bounds__(256) void tnorm(const float* __restrict__ x,
                                             const float* __restrict__ stats,
                                             const float* __restrict__ gw,
                                             const float* __restrict__ gb,
                                             short* __restrict__ xT,
                                             short* __restrict__ nT) {
  __shared__ float tile[64 * 65];
  int b = blockIdx.z, c0 = blockIdx.y * 64, s0 = blockIdx.x * 64;
  int t = threadIdx.x;
  const float* xp = x + ((size_t)b * NC + c0) * NS + s0;
#pragma unroll
  for (int p = 0; p < 4; p++) {
    int idx = p * 256 + t;
    int cl = idx >> 4;
    int s4 = (idx & 15) * 4;
    float4 v = *(const float4*)(xp + (size_t)cl * NS + s4);
    tile[cl * 65 + s4 + 0] = v.x;
    tile[cl * 65 + s4 + 1] = v.y;
    tile[cl * 65 + s4 + 2] = v.z;
    tile[cl * 65 + s4 + 3] = v.w;
  }
  __syncthreads();
#pragma unroll
  for (int p = 0; p < 4; p++) {
    int idx = p * 256 + t;
    int sl = idx >> 4;
    int c4 = (idx & 15) * 4;
    size_t ob = ((size_t)b * NS + s0 + sl) * NC + c0 + c4;
    s16x4 xo, no;
#pragma unroll
    for (int j = 0; j < 4; j++) {
      int c = c0 + c4 + j;
      float val = tile[(c4 + j) * 65 + sl];
      int g = c >> 4;
      float mu = stats[(b * GN_GROUPS + g) * 2];
      float rs = stats[(b * GN_GROUPS + g) * 2 + 1];
      float nv = (val - mu) * rs * gw[c] + gb[c];
      xo[j] = f2bf(val);
      no[j] = f2bf(nv);
    }
    *(s16x4*)(xT + ob) = xo;
    *(s16x4*)(nT + ob) = no;
  }
}

// ---------------- kernel 3: fused q/k/v GEMM, BK=64; v written transposed [B,H,D,S] ----------------
// 128x128 tile, 8 K-iters of 64 (halved barrier count vs BK=32).
// Panels 128x64 shorts, 8-chunk XOR swizzle (chunk ^= row&7) on store+read.
__global__ __launch_bounds__(256) void gemm_qkv(const short* __restrict__ nT,
                                                const short* __restrict__ xT,
                                                const short* __restrict__ wq,
                                                const short* __restrict__ wk,
                                                const short* __restrict__ wv,
                                                short* __restrict__ q,
                                                short* __restrict__ k,
                                                short* __restrict__ vt) {
  __shared__ __attribute__((aligned(16))) short sA[128 * 64];
  __shared__ __attribute__((aligned(16))) short sB[128 * 64];
  int proj = blockIdx.y >> 2;
  int n0 = (blockIdx.y & 3) * 128;
  int m0 = blockIdx.x * 128;
  const short* A  = (proj == 0) ? nT : xT;
  const short* Bm = (proj == 0) ? wq : ((proj == 1) ? wk : wv);
  short* Out      = (proj == 0) ? q  : ((proj == 1) ? k  : vt);

  int tid = threadIdx.x, lane = tid & 63, w = tid >> 6;
  int quad = lane >> 4, l16 = lane & 15;
  int m_off = (w >> 1) * 64, n_off = (w & 1) * 64;
  int r8 = lane >> 3, cd = lane & 7;  // staging: 8 rows/inst, 8 chunks/row

  f32x4 acc[4][4] = {};

  for (int kk = 0; kk < 512; kk += 64) {
    __syncthreads();
#pragma unroll
    for (int i = 0; i < 4; i++) {
      int rl = w * 32 + i * 8 + r8;
      int cs = (cd ^ (rl & 7)) * 8;
      async_lds16(A  + (size_t)(m0 + rl) * 512 + kk + cs, &sA[(w * 32 + i * 8) * 64]);
      async_lds16(Bm + (size_t)(n0 + rl) * 512 + kk + cs, &sB[(w * 32 + i * 8) * 64]);
    }
    __syncthreads();
#pragma unroll
    for (int ks = 0; ks < 2; ks++) {
      bf16x8 aF[4], bF[4];
#pragma unroll
      for (int ms = 0; ms < 4; ms++) {
        int row = m_off + ms * 16 + l16;
        aF[ms] = *(const bf16x8*)&sA[row * 64 + (((ks * 4 + quad) ^ (row & 7)) * 8)];
      }
#pragma unroll
      for (int ns = 0; ns < 4; ns++) {
        int row = n_off + ns * 16 + l16;
        bF[ns] = *(const bf16x8*)&sB[row * 64 + (((ks * 4 + quad) ^ (row & 7)) * 8)];
      }
#pragma unroll
      for (int ms = 0; ms < 4; ms++)
#pragma unroll
        for (int ns = 0; ns < 4; ns++)
          acc[ms][ns] = MFMA16(aF[ms], bF[ns], acc[ms][ns]);
    }
  }
  if (proj < 2) {
#pragma unroll
    for (int ms = 0; ms < 4; ms++)
#pragma unroll
      for (int ns = 0; ns < 4; ns++)
#pragma unroll
        for (int r = 0; r < 4; r++) {
          int row = m0 + m_off + ms * 16 + quad * 4 + r;
          int col = n0 + n_off + ns * 16 + l16;
          Out[(size_t)row * 512 + col] = f2bf(acc[ms][ns][r]);
        }
  } else {
    // transposed store: vT[b, h=col>>6, d=col&63, s] ; 4 consecutive s per lane
#pragma unroll
    for (int ms = 0; ms < 4; ms++)
#pragma unroll
      for (int ns = 0; ns < 4; ns++) {
        int rowb = m0 + m_off + ms * 16 + quad * 4;  // s base (4 consecutive)
        int col  = n0 + n_off + ns * 16 + l16;       // channel
        int bb = rowb >> 10, s = rowb & 1023;
        s16x4 pk4;
#pragma unroll
        for (int r = 0; r < 4; r++) pk4[r] = f2bf(acc[ms][ns][r]);
        *(s16x4*)&Out[((size_t)(bb * NC + col)) * NS + s] = pk4;
      }
  }
}

// ---------------- kernel 4: flash attention, split-KV in-block ----------------
// grid (64 b*h, 8 q-tiles of 128); block 512 = 8 waves.
// Wave-group wg=w>>2 handles KV tiles wg*8..wg*8+7 with private double-buffered
// panels; exact merge (no max-subtraction): O=O0+O1, l=l0+l1 via LDS exchange.
__global__ __launch_bounds__(512, 4) void attn(const short* __restrict__ q,
                                               const short* __restrict__ k,
                                               const short* __restrict__ vT,
                                               short* __restrict__ ctx) {
  __shared__ __attribute__((aligned(16))) short smem[32768];  // 64 KB
#define SKp(wg, p, hf) (&smem[((wg) * 4 + (p) * 2 + (hf)) * 2048])
#define SVp(wg, p, c)  (&smem[16384 + ((wg) * 4 + (p) * 2 + (c)) * 2048])
  int b = blockIdx.x >> 3, h = blockIdx.x & 7;
  int q0 = blockIdx.y * 128;
  int tid = threadIdx.x, lane = tid & 63, w = tid >> 6;
  int wg = w >> 2, wl = w & 3;
  int quad = lane >> 4, l16 = lane & 15;

  const short* kb = k  + (size_t)b * (NS * NC) + h * DH;
  const short* vb = vT + (size_t)(b * NH + h) * (DH * NS);

  // Q B-frags (persistent): B[n=q(l16)][k=d(quad*8+j)]  (same for both groups)
  bf16x8 qf[2][2];
#pragma unroll
  for (int g = 0; g < 2; g++) {
    const short* qp = q + ((size_t)(b * NS + q0 + g * 64 + wl * 16 + l16)) * NC + h * DH + quad * 8;
    qf[g][0] = *(const bf16x8*)qp;
    qf[g][1] = *(const bf16x8*)(qp + 32);
  }

  int sr4  = lane >> 2;
  int srow = wl * 16 + sr4;                         // panel row (0..63)
  int csw  = ((lane & 3) ^ ((sr4 >> 1) & 3)) * 8;   // swizzled source chunk
  int rsw  = (quad ^ ((l16 >> 1) & 3)) * 8;         // swizzled frag-read chunk

#define STAGE(p, kt) do {                                              \
    int kv0_ = (wg * 8 + (kt)) * 64;                                   \
    const short* kg_ = kb + (size_t)(kv0_ + srow) * NC + csw;          \
    async_lds16(kg_,      SKp(wg, p, 0) + wl * 512);                   \
    async_lds16(kg_ + 32, SKp(wg, p, 1) + wl * 512);                   \
    const short* vg_ = vb + (size_t)srow * NS + kv0_ + csw;            \
    async_lds16(vg_,      SVp(wg, p, 0) + wl * 512);                   \
    async_lds16(vg_ + 32, SVp(wg, p, 1) + wl * 512);                   \
  } while (0)

  STAGE(0, 0);

  f32x4 o[2][4] = {};
  float lsum[2] = {0.f, 0.f};
  int src0 = (quad & 1) * 32 + l16;
  int src1 = src0 + 16;
  int selB = quad >> 1;

  for (int kt = 0; kt < 8; kt++) {
    int p = kt & 1;
    __syncthreads();
    if (kt < 7) STAGE(1 - p, kt + 1);

    f32x4 sc[2][4];
#pragma unroll
    for (int mt = 0; mt < 4; mt++) {
      bf16x8 ak0 = *(const bf16x8*)(SKp(wg, p, 0) + (mt * 16 + l16) * 32 + rsw);
      bf16x8 ak1 = *(const bf16x8*)(SKp(wg, p, 1) + (mt * 16 + l16) * 32 + rsw);
#pragma unroll
      for (int g = 0; g < 2; g++) {
        f32x4 z = {0.f, 0.f, 0.f, 0.f};
        z = MFMA16(ak0, qf[g][0], z);
        z = MFMA16(ak1, qf[g][1], z);
        sc[g][mt] = z;
      }
    }
    int pk[2][4][2];
#pragma unroll
    for (int g = 0; g < 2; g++)
#pragma unroll
      for (int mt = 0; mt < 4; mt++)
#pragma unroll
        for (int hh = 0; hh < 2; hh++) {
          float e0 = EXP2(sc[g][mt][2 * hh]);
          float e1 = EXP2(sc[g][mt][2 * hh + 1]);
          lsum[g] += e0 + e1;
          pk[g][mt][hh] = pack2bf_fast(e0, e1);
        }
    bf16x8 pf[2][2];
#pragma unroll
    for (int g = 0; g < 2; g++)
#pragma unroll
      for (int c = 0; c < 2; c++) {
        union { int d[4]; bf16x8 v; } u;
#pragma unroll
        for (int dd = 0; dd < 4; dd++) {
          int s = (dd >> 1) ? src1 : src0;
          int A = __shfl(pk[g][2 * c][dd & 1], s, 64);
          int B = __shfl(pk[g][2 * c + 1][dd & 1], s, 64);
          u.d[dd] = selB ? B : A;
        }
        pf[g][c] = u.v;
      }
#pragma unroll
    for (int dt = 0; dt < 4; dt++) {
      bf16x8 av0 = *(const bf16x8*)(SVp(wg, p, 0) + (dt * 16 + l16) * 32 + rsw);
      bf16x8 av1 = *(const bf16x8*)(SVp(wg, p, 1) + (dt * 16 + l16) * 32 + rsw);
#pragma unroll
      for (int g = 0; g < 2; g++) {
        o[g][dt] = MFMA16(av0, pf[g][0], o[g][dt]);
        o[g][dt] = MFMA16(av1, pf[g][1], o[g][dt]);
      }
    }
  }
  // per-wave quad reduction of denominator
#pragma unroll
  for (int g = 0; g < 2; g++) {
    lsum[g] += __shfl_xor(lsum[g], 16, 64);
    lsum[g] += __shfl_xor(lsum[g], 32, 64);
  }
  // cross-group combine (panels dead after this barrier)
  float* dump  = (float*)smem;            // 32 KB (SK region)
  float* lsums = (float*)&smem[16384];    // 512 B (SV region)
  __syncthreads();
  if (wg == 1) {
#pragma unroll
    for (int g = 0; g < 2; g++) {
#pragma unroll
      for (int dt = 0; dt < 4; dt++)
        *(f32x4*)&dump[((((g * 4 + wl) * 4) + dt) * 64 + lane) * 4] = o[g][dt];
      if (quad == 0) lsums[(g * 4 + wl) * 16 + l16] = lsum[g];
    }
  }
  __syncthreads();
  float inv[2];
  if (wg == 0) {
#pragma unroll
    for (int g = 0; g < 2; g++) {
      inv[g] = 1.f / (lsum[g] + lsums[(g * 4 + wl) * 16 + l16]);
#pragma unroll
      for (int dt = 0; dt < 4; dt++) {
        f32x4 add = *(const f32x4*)&dump[((((g * 4 + wl) * 4) + dt) * 64 + lane) * 4];
        o[g][dt] += add;
      }
    }
  }
  __syncthreads();
  // epilogue: O^T (row=d, col=q) -> LDS transpose -> coalesced ctx [B,S,C]
  short* sT = &smem[0];  // 128 q-rows x 72 (18 KB, reuses dump region)
  if (wg == 0) {
#pragma unroll
    for (int g = 0; g < 2; g++)
#pragma unroll
      for (int dt = 0; dt < 4; dt++)
#pragma unroll
        for (int r = 0; r < 4; r++)
          sT[(g * 64 + wl * 16 + l16) * 72 + dt * 16 + quad * 4 + r] = f2bf(o[g][dt][r] * inv[g]);
  }
  __syncthreads();
  for (int it = tid; it < 1024; it += 512) {
    int row = it >> 3, ch = (it & 7) * 8;
    *(bf16x8*)&ctx[((size_t)(b * NS + q0 + row)) * NC + h * DH + ch] =
        *(const bf16x8*)&sT[row * 72 + ch];
  }
#undef STAGE
#undef SKp
#undef SVp
}

// ---------------- kernel 5: out = ctx @ Wo^T + bo, 64x128 tile, BK=64, store [B,C,S] fp32 ----------------
__global__ __launch_bounds__(256) void gemm_out(const short* __restrict__ ctx,
                                                const short* __restrict__ wo,
                                                const float* __restrict__ bo,
                                                float* __restrict__ out) {
  __shared__ __attribute__((aligned(16))) short sA[64 * 64];
  __shared__ __attribute__((aligned(16))) short sB[128 * 64];
  int n0 = blockIdx.y * 128;
  int m0 = blockIdx.x * 64;
  int tid = threadIdx.x, lane = tid & 63, w = tid >> 6;
  int quad = lane >> 4, l16 = lane & 15;
  int r8 = lane >> 3, cd = lane & 7;

  f32x4 acc[4][2] = {};

  for (int kk = 0; kk < 512; kk += 64) {
    __syncthreads();
    {
      int rlA = w * 16 + r8;  // 64 A-rows: 16/wave, 2 insts
      int csA0 = (cd ^ (rlA & 7)) * 8;
      int csA1 = (cd ^ ((rlA + 8) & 7)) * 8;
      async_lds16(ctx + (size_t)(m0 + rlA)     * 512 + kk + csA0, &sA[(w * 16) * 64]);
      async_lds16(ctx + (size_t)(m0 + rlA + 8) * 512 + kk + csA1, &sA[(w * 16 + 8) * 64]);
#pragma unroll
      for (int i = 0; i < 4; i++) {
        int rl = w * 32 + i * 8 + r8;
        int cs = (cd ^ (rl & 7)) * 8;
        async_lds16(wo + (size_t)(n0 + rl) * 512 + kk + cs, &sB[(w * 32 + i * 8) * 64]);
      }
    }
    __syncthreads();
#pragma unroll
    for (int ks = 0; ks < 2; ks++) {
      bf16x8 aF[4], bF[2];
#pragma unroll
      for (int ms = 0; ms < 4; ms++) {
        int row = ms * 16 + l16;
        aF[ms] = *(const bf16x8*)&sA[row * 64 + (((ks * 4 + quad) ^ (row & 7)) * 8)];
      }
#pragma unroll
      for (int ns = 0; ns < 2; ns++) {
        int row = w * 32 + ns * 16 + l16;
        bF[ns] = *(const bf16x8*)&sB[row * 64 + (((ks * 4 + quad) ^ (row & 7)) * 8)];
      }
#pragma unroll
      for (int ms = 0; ms < 4; ms++)
#pragma unroll
        for (int ns = 0; ns < 2; ns++)
          acc[ms][ns] = MFMA16(aF[ms], bF[ns], acc[ms][ns]);
    }
  }
#pragma unroll
  for (int ms = 0; ms < 4; ms++)
#pragma unroll
    for (int ns = 0; ns < 2; ns++)
#pragma unroll
      for (int r = 0; r < 4; r++) {
        int row = m0 + ms * 16 + quad * 4 + r;
        int col = n0 + w * 32 + ns * 16 + l16;
        int bb = row >> 10, s = row & 1023;
        out[((size_t)(bb * NC + col)) * NS + s] = acc[ms][ns][r] + bo[col];
      }
}

extern "C" void kernel_launch(void* const* d_in, const int* in_sizes, int n_in,
                              void* d_out, int out_size, void* d_ws, size_t ws_size,
                              hipStream_t stream) {
  const float* x  = (const float*)d_in[0];
  const float* gw = (const float*)d_in[1];
  const float* gb = (const float*)d_in[2];
  const float* Wq = (const float*)d_in[3];
  const float* Wk = (const float*)d_in[4];
  const float* Wv = (const float*)d_in[5];
  const float* Wo = (const float*)d_in[6];
  const float* bo = (const float*)d_in[7];
  float* out = (float*)d_out;

  char* ws = (char*)d_ws;
  const size_t MAT = (size_t)8192 * 512 * 2;  // 8 MB bf16
  float* stats = (float*)ws;
  short* xT  = (short*)(ws + 4096);
  short* nT  = (short*)(ws + 4096 + 1 * MAT);
  short* q   = (short*)(ws + 4096 + 2 * MAT);
  short* k   = (short*)(ws + 4096 + 3 * MAT);
  short* vt  = (short*)(ws + 4096 + 4 * MAT);  // V^T [B,H,D,S]
  short* ctx = (short*)(ws + 4096 + 5 * MAT);
  short* wqb = (short*)(ws + 4096 + 6 * MAT);
  short* wkb = wqb + 262144;
  short* wvb = wkb + 262144;
  short* wob = wvb + 262144;

  const float qscale = 0.125f * 1.44269504088896f;  // d^-0.5 * log2(e), folded into Wq
  prep<<<1280, 256, 0, stream>>>(x, stats,
                                 (const float4*)Wq, (const float4*)Wk,
                                 (const float4*)Wv, (const float4*)Wo,
                                 (s16x4*)wqb, (s16x4*)wkb, (s16x4*)wvb, (s16x4*)wob,
                                 qscale);
  tnorm<<<dim3(16, 8, 8), 256, 0, stream>>>(x, stats, gw, gb, xT, nT);
  gemm_qkv<<<dim3(64, 12), 256, 0, stream>>>(nT, xT, wqb, wkb, wvb, q, k, vt);
  attn<<<dim3(64, 8), 512, 0, stream>>>(q, k, vt, ctx);
  gemm_out<<<dim3(128, 4), 256, 0, stream>>>(ctx, wob, bo, out);
}

// Round 9
// 149.366 us; speedup vs baseline: 1.0287x; 1.0287x over previous
//
#include <hip/hip_runtime.h>
#include <hip/hip_bf16.h>

typedef short bf16x8 __attribute__((ext_vector_type(8)));
typedef short s16x4  __attribute__((ext_vector_type(4)));
typedef float f32x4  __attribute__((ext_vector_type(4)));

#define NB 8
#define NC 512
#define NS 1024
#define NH 8
#define DH 64
#define GN_GROUPS 32
#define GN_EPS 1e-5f

#if __has_builtin(__builtin_amdgcn_exp2f)
#define EXP2(x) __builtin_amdgcn_exp2f(x)
#else
#define EXP2(x) __expf((x) * 0.69314718056f)
#endif

static __device__ __forceinline__ short f2bf(float f) {
  union { __hip_bfloat16 h; short s; } u;
  u.h = __float2bfloat16(f);
  return u.s;
}

// round-to-nearest (ties up) bf16 pair pack: 2 adds + 1 v_perm_b32
static __device__ __forceinline__ int pack2bf_fast(float a, float b) {
  unsigned ua = __float_as_uint(a) + 0x8000u;
  unsigned ub = __float_as_uint(b) + 0x8000u;
  return (int)__builtin_amdgcn_perm(ub, ua, 0x07060302u);  // a in low 16 bits
}

static __device__ __forceinline__ void async_lds16(const void* g, void* l) {
  __builtin_amdgcn_global_load_lds((__attribute__((address_space(1))) void*)(g),
                                   (__attribute__((address_space(3))) void*)(l),
                                   16, 0, 0);
}

#define MFMA16(a, b, c) __builtin_amdgcn_mfma_f32_16x16x32_bf16((a), (b), (c), 0, 0, 0)

// ---------------- kernel 1: weight convert + groupnorm stats (one launch) ----------------
__global__ __launch_bounds__(256) void prep(const float* __restrict__ x,
                                            float* __restrict__ stats,
                                            const float4* __restrict__ Wq,
                                            const float4* __restrict__ Wk,
                                            const float4* __restrict__ Wv,
                                            const float4* __restrict__ Wo,
                                            s16x4* __restrict__ oq, s16x4* __restrict__ ok,
                                            s16x4* __restrict__ ov, s16x4* __restrict__ oo,
                                            float qscale) {
  if (blockIdx.x < 256) {  // groupnorm stats: block per (b,g)
    int bg = blockIdx.x;
    const float4* p = (const float4*)(x + (size_t)bg * 16384);
    float s = 0.f, s2 = 0.f;
    for (int i = threadIdx.x; i < 4096; i += 256) {
      float4 v = p[i];
      s  += v.x + v.y + v.z + v.w;
      s2 += v.x * v.x + v.y * v.y + v.z * v.z + v.w * v.w;
    }
    for (int off = 32; off > 0; off >>= 1) {
      s  += __shfl_down(s, off, 64);
      s2 += __shfl_down(s2, off, 64);
    }
    __shared__ float red[8];
    int w = threadIdx.x >> 6;
    if ((threadIdx.x & 63) == 0) { red[w * 2] = s; red[w * 2 + 1] = s2; }
    __syncthreads();
    if (threadIdx.x == 0) {
      float S = 0.f, S2 = 0.f;
      for (int i = 0; i < 4; i++) { S += red[i * 2]; S2 += red[i * 2 + 1]; }
      float mu  = S / 16384.f;
      float var = S2 / 16384.f - mu * mu;
      stats[bg * 2]     = mu;
      stats[bg * 2 + 1] = rsqrtf(var + GN_EPS);
    }
  } else {  // weight fp32 -> bf16
    int idx = blockIdx.x - 256;
    int sel = idx >> 8;
    int i = (idx & 255) * 256 + threadIdx.x;
    const float4* src = (sel == 0) ? Wq : (sel == 1) ? Wk : (sel == 2) ? Wv : Wo;
    s16x4* dst        = (sel == 0) ? oq : (sel == 1) ? ok : (sel == 2) ? ov : oo;
    float scale = (sel == 0) ? qscale : 1.0f;
    float4 f = src[i];
    s16x4 o;
    o[0] = f2bf(f.x * scale); o[1] = f2bf(f.y * scale);
    o[2] = f2bf(f.z * scale); o[3] = f2bf(f.w * scale);
    dst[i] = o;
  }
}

// ---------------- kernel 2: transpose + groupnorm apply ----------------
__global__ __launch_bounds__(256) void tnorm(const float* __restrict__ x,
                                             const float* __restrict__ stats,
                                             const float* __restrict__ gw,
                                             const float* __restrict__ gb,
                                             short* __restrict__ xT,
                                             short* __restrict__ nT) {
  __shared__ float tile[64 * 65];
  int b = blockIdx.z, c0 = blockIdx.y * 64, s0 = blockIdx.x * 64;
  int t = threadIdx.x;
  const float* xp = x + ((size_t)b * NC + c0) * NS + s0;
#pragma unroll
  for (int p = 0; p < 4; p++) {
    int idx = p * 256 + t;
    int cl = idx >> 4;
    int s4 = (idx & 15) * 4;
    float4 v = *(const float4*)(xp + (size_t)cl * NS + s4);
    tile[cl * 65 + s4 + 0] = v.x;
    tile[cl * 65 + s4 + 1] = v.y;
    tile[cl * 65 + s4 + 2] = v.z;
    tile[cl * 65 + s4 + 3] = v.w;
  }
  __syncthreads();
#pragma unroll
  for (int p = 0; p < 4; p++) {
    int idx = p * 256 + t;
    int sl = idx >> 4;
    int c4 = (idx & 15) * 4;
    size_t ob = ((size_t)b * NS + s0 + sl) * NC + c0 + c4;
    s16x4 xo, no;
#pragma unroll
    for (int j = 0; j < 4; j++) {
      int c = c0 + c4 + j;
      float val = tile[(c4 + j) * 65 + sl];
      int g = c >> 4;
      float mu = stats[(b * GN_GROUPS + g) * 2];
      float rs = stats[(b * GN_GROUPS + g) * 2 + 1];
      float nv = (val - mu) * rs * gw[c] + gb[c];
      xo[j] = f2bf(val);
      no[j] = f2bf(nv);
    }
    *(s16x4*)(xT + ob) = xo;
    *(s16x4*)(nT + ob) = no;
  }
}

// ---------------- kernel 3: fused q/k/v GEMM (BK=32, XOR swizzle, vectorized epilogue) ----------------
__global__ __launch_bounds__(256) void gemm_qkv(const short* __restrict__ nT,
                                                const short* __restrict__ xT,
                                                const short* __restrict__ wq,
                                                const short* __restrict__ wk,
                                                const short* __restrict__ wv,
                                                short* __restrict__ q,
                                                short* __restrict__ k,
                                                short* __restrict__ vt) {
  __shared__ __attribute__((aligned(16))) short smem[8704];  // panels 2x4096; epilogue 64x136
  short* sA = smem;
  short* sB = smem + 4096;
  int proj = blockIdx.y >> 2;
  int n0 = (blockIdx.y & 3) * 128;
  int m0 = blockIdx.x * 128;
  const short* A  = (proj == 0) ? nT : xT;
  const short* Bm = (proj == 0) ? wq : ((proj == 1) ? wk : wv);
  short* Out      = (proj == 0) ? q  : ((proj == 1) ? k  : vt);

  int tid = threadIdx.x, lane = tid & 63, w = tid >> 6;
  int quad = lane >> 4, l16 = lane & 15;
  int m_off = (w >> 1) * 64, n_off = (w & 1) * 64;
  int sr4 = lane >> 2;
  int csw = ((lane & 3) ^ ((sr4 >> 1) & 3)) * 8;
  int rsw = (quad ^ ((l16 >> 1) & 3)) * 8;

  const short* gA = A  + ((size_t)(m0 + w * 32 + sr4)) * 512 + csw;
  const short* gB = Bm + ((size_t)(n0 + w * 32 + sr4)) * 512 + csw;
  short* lA = &sA[w * 1024];
  short* lB = &sB[w * 1024];

  f32x4 acc[4][4] = {};

  for (int kk = 0; kk < 512; kk += 32) {
    __syncthreads();
    async_lds16(gA + kk,            lA);
    async_lds16(gA + kk + 16 * 512, lA + 512);
    async_lds16(gB + kk,            lB);
    async_lds16(gB + kk + 16 * 512, lB + 512);
    __syncthreads();
    bf16x8 aF[4], bF[4];
#pragma unroll
    for (int ms = 0; ms < 4; ms++)
      aF[ms] = *(const bf16x8*)&sA[(m_off + ms * 16 + l16) * 32 + rsw];
#pragma unroll
    for (int ns = 0; ns < 4; ns++)
      bF[ns] = *(const bf16x8*)&sB[(n_off + ns * 16 + l16) * 32 + rsw];
#pragma unroll
    for (int ms = 0; ms < 4; ms++)
#pragma unroll
      for (int ns = 0; ns < 4; ns++)
        acc[ms][ns] = MFMA16(aF[ms], bF[ns], acc[ms][ns]);
  }
  if (proj < 2) {
    // LDS-transpose epilogue: two 64-row halves, dwordx4 global stores
    short* sT = smem;  // 64 x 136 (272 B rows: 16B-aligned, bank-rotated)
    int hown = m_off >> 6;
#pragma unroll
    for (int hm = 0; hm < 2; hm++) {
      __syncthreads();
      if (hown == hm) {
#pragma unroll
        for (int ms = 0; ms < 4; ms++)
#pragma unroll
          for (int ns = 0; ns < 4; ns++)
#pragma unroll
            for (int r = 0; r < 4; r++)
              sT[(ms * 16 + quad * 4 + r) * 136 + n_off + ns * 16 + l16] = f2bf(acc[ms][ns][r]);
      }
      __syncthreads();
#pragma unroll
      for (int p2 = 0; p2 < 4; p2++) {
        int idx = p2 * 256 + tid;
        int row = idx >> 4, ch = (idx & 15) * 8;
        *(bf16x8*)&Out[(size_t)(m0 + hm * 64 + row) * 512 + n0 + ch] =
            *(const bf16x8*)&sT[row * 136 + ch];
      }
    }
  } else {
    // transposed store: vT[b, h=col>>6, d=col&63, s] ; 4 consecutive s per lane
#pragma unroll
    for (int ms = 0; ms < 4; ms++)
#pragma unroll
      for (int ns = 0; ns < 4; ns++) {
        int rowb = m0 + m_off + ms * 16 + quad * 4;  // s base (4 consecutive)
        int col  = n0 + n_off + ns * 16 + l16;       // channel
        int bb = rowb >> 10, s = rowb & 1023;
        s16x4 pk4;
#pragma unroll
        for (int r = 0; r < 4; r++) pk4[r] = f2bf(acc[ms][ns][r]);
        *(s16x4*)&Out[((size_t)(bb * NC + col)) * NS + s] = pk4;
      }
  }
}

// ---------------- kernel 4: flash attention, split-KV in-block ----------------
// grid (64 b*h, 8 q-tiles of 128); block 512 = 8 waves.
// Wave-group wg=w>>2 handles KV tiles wg*8..wg*8+7 with private double-buffered
// panels; exact merge (no max-subtraction): O=O0+O1, l=l0+l1 via LDS exchange.
__global__ __launch_bounds__(512, 4) void attn(const short* __restrict__ q,
                                               const short* __restrict__ k,
                                               const short* __restrict__ vT,
                                               short* __restrict__ ctx) {
  __shared__ __attribute__((aligned(16))) short smem[32768];  // 64 KB
#define SKp(wg, p, hf) (&smem[((wg) * 4 + (p) * 2 + (hf)) * 2048])
#define SVp(wg, p, c)  (&smem[16384 + ((wg) * 4 + (p) * 2 + (c)) * 2048])
  int b = blockIdx.x >> 3, h = blockIdx.x & 7;
  int q0 = blockIdx.y * 128;
  int tid = threadIdx.x, lane = tid & 63, w = tid >> 6;
  int wg = w >> 2, wl = w & 3;
  int quad = lane >> 4, l16 = lane & 15;

  const short* kb = k  + (size_t)b * (NS * NC) + h * DH;
  const short* vb = vT + (size_t)(b * NH + h) * (DH * NS);

  // Q B-frags (persistent): B[n=q(l16)][k=d(quad*8+j)]  (same for both groups)
  bf16x8 qf[2][2];
#pragma unroll
  for (int g = 0; g < 2; g++) {
    const short* qp = q + ((size_t)(b * NS + q0 + g * 64 + wl * 16 + l16)) * NC + h * DH + quad * 8;
    qf[g][0] = *(const bf16x8*)qp;
    qf[g][1] = *(const bf16x8*)(qp + 32);
  }

  int sr4  = lane >> 2;
  int srow = wl * 16 + sr4;                         // panel row (0..63)
  int csw  = ((lane & 3) ^ ((sr4 >> 1) & 3)) * 8;   // swizzled source chunk
  int rsw  = (quad ^ ((l16 >> 1) & 3)) * 8;         // swizzled frag-read chunk

#define STAGE(p, kt) do {                                              \
    int kv0_ = (wg * 8 + (kt)) * 64;                                   \
    const short* kg_ = kb + (size_t)(kv0_ + srow) * NC + csw;          \
    async_lds16(kg_,      SKp(wg, p, 0) + wl * 512);                   \
    async_lds16(kg_ + 32, SKp(wg, p, 1) + wl * 512);                   \
    const short* vg_ = vb + (size_t)srow * NS + kv0_ + csw;            \
    async_lds16(vg_,      SVp(wg, p, 0) + wl * 512);                   \
    async_lds16(vg_ + 32, SVp(wg, p, 1) + wl * 512);                   \
  } while (0)

  STAGE(0, 0);

  f32x4 o[2][4] = {};
  float lsum[2] = {0.f, 0.f};
  int src0 = (quad & 1) * 32 + l16;
  int src1 = src0 + 16;
  int selB = quad >> 1;

  for (int kt = 0; kt < 8; kt++) {
    int p = kt & 1;
    __syncthreads();
    if (kt < 7) STAGE(1 - p, kt + 1);

    f32x4 sc[2][4];
#pragma unroll
    for (int mt = 0; mt < 4; mt++) {
      bf16x8 ak0 = *(const bf16x8*)(SKp(wg, p, 0) + (mt * 16 + l16) * 32 + rsw);
      bf16x8 ak1 = *(const bf16x8*)(SKp(wg, p, 1) + (mt * 16 + l16) * 32 + rsw);
#pragma unroll
      for (int g = 0; g < 2; g++) {
        f32x4 z = {0.f, 0.f, 0.f, 0.f};
        z = MFMA16(ak0, qf[g][0], z);
        z = MFMA16(ak1, qf[g][1], z);
        sc[g][mt] = z;
      }
    }
    int pk[2][4][2];
#pragma unroll
    for (int g = 0; g < 2; g++)
#pragma unroll
      for (int mt = 0; mt < 4; mt++)
#pragma unroll
        for (int hh = 0; hh < 2; hh++) {
          float e0 = EXP2(sc[g][mt][2 * hh]);
          float e1 = EXP2(sc[g][mt][2 * hh + 1]);
          lsum[g] += e0 + e1;
          pk[g][mt][hh] = pack2bf_fast(e0, e1);
        }
    bf16x8 pf[2][2];
#pragma unroll
    for (int g = 0; g < 2; g++)
#pragma unroll
      for (int c = 0; c < 2; c++) {
        union { int d[4]; bf16x8 v; } u;
#pragma unroll
        for (int dd = 0; dd < 4; dd++) {
          int s = (dd >> 1) ? src1 : src0;
          int A = __shfl(pk[g][2 * c][dd & 1], s, 64);
          int B = __shfl(pk[g][2 * c + 1][dd & 1], s, 64);
          u.d[dd] = selB ? B : A;
        }
        pf[g][c] = u.v;
      }
#pragma unroll
    for (int dt = 0; dt < 4; dt++) {
      bf16x8 av0 = *(const bf16x8*)(SVp(wg, p, 0) + (dt * 16 + l16) * 32 + rsw);
      bf16x8 av1 = *(const bf16x8*)(SVp(wg, p, 1) + (dt * 16 + l16) * 32 + rsw);
#pragma unroll
      for (int g = 0; g < 2; g++) {
        o[g][dt] = MFMA16(av0, pf[g][0], o[g][dt]);
        o[g][dt] = MFMA16(av1, pf[g][1], o[g][dt]);
      }
    }
  }
  // per-wave quad reduction of denominator
#pragma unroll
  for (int g = 0; g < 2; g++) {
    lsum[g] += __shfl_xor(lsum[g], 16, 64);
    lsum[g] += __shfl_xor(lsum[g], 32, 64);
  }
  // cross-group combine (panels dead after this barrier)
  float* dump  = (float*)smem;            // 32 KB (SK region)
  float* lsums = (float*)&smem[16384];    // 512 B (SV region)
  __syncthreads();
  if (wg == 1) {
#pragma unroll
    for (int g = 0; g < 2; g++) {
#pragma unroll
      for (int dt = 0; dt < 4; dt++)
        *(f32x4*)&dump[((((g * 4 + wl) * 4) + dt) * 64 + lane) * 4] = o[g][dt];
      if (quad == 0) lsums[(g * 4 + wl) * 16 + l16] = lsum[g];
    }
  }
  __syncthreads();
  float inv[2];
  if (wg == 0) {
#pragma unroll
    for (int g = 0; g < 2; g++) {
      inv[g] = 1.f / (lsum[g] + lsums[(g * 4 + wl) * 16 + l16]);
#pragma unroll
      for (int dt = 0; dt < 4; dt++) {
        f32x4 add = *(const f32x4*)&dump[((((g * 4 + wl) * 4) + dt) * 64 + lane) * 4];
        o[g][dt] += add;
      }
    }
  }
  __syncthreads();
  // epilogue: O^T (row=d, col=q) -> LDS transpose -> coalesced ctx [B,S,C]
  short* sT = &smem[0];  // 128 q-rows x 72 (18 KB, reuses dump region)
  if (wg == 0) {
#pragma unroll
    for (int g = 0; g < 2; g++)
#pragma unroll
      for (int dt = 0; dt < 4; dt++)
#pragma unroll
        for (int r = 0; r < 4; r++)
          sT[(g * 64 + wl * 16 + l16) * 72 + dt * 16 + quad * 4 + r] = f2bf(o[g][dt][r] * inv[g]);
  }
  __syncthreads();
  for (int it = tid; it < 1024; it += 512) {
    int row = it >> 3, ch = (it & 7) * 8;
    *(bf16x8*)&ctx[((size_t)(b * NS + q0 + row)) * NC + h * DH + ch] =
        *(const bf16x8*)&sT[row * 72 + ch];
  }
#undef STAGE
#undef SKp
#undef SVp
}

// ---------------- kernel 5: out = ctx @ Wo^T + bo, 64x128 tiles, f32x4 stores ----------------
__global__ __launch_bounds__(256) void gemm_out(const short* __restrict__ ctx,
                                                const short* __restrict__ wo,
                                                const float* __restrict__ bo,
                                                float* __restrict__ out) {
  __shared__ __attribute__((aligned(16))) short sA[64 * 32];
  __shared__ __attribute__((aligned(16))) short sB[128 * 32];
  int n0 = blockIdx.y * 128;
  int m0 = blockIdx.x * 64;
  int tid = threadIdx.x, lane = tid & 63, w = tid >> 6;
  int quad = lane >> 4, l16 = lane & 15;
  int sr4 = lane >> 2;
  int csw = ((lane & 3) ^ ((sr4 >> 1) & 3)) * 8;
  int rsw = (quad ^ ((l16 >> 1) & 3)) * 8;

  const short* gA = ctx + ((size_t)(m0 + w * 16 + sr4)) * 512 + csw;
  const short* gB = wo  + ((size_t)(n0 + w * 32 + sr4)) * 512 + csw;
  short* lA = &sA[w * 512];
  short* lB = &sB[w * 1024];

  f32x4 acc[4][2] = {};

  for (int kk = 0; kk < 512; kk += 32) {
    __syncthreads();
    async_lds16(gA + kk,            lA);
    async_lds16(gB + kk,            lB);
    async_lds16(gB + kk + 16 * 512, lB + 512);
    __syncthreads();
    bf16x8 aF[4], bF[2];
#pragma unroll
    for (int ms = 0; ms < 4; ms++)
      aF[ms] = *(const bf16x8*)&sA[(ms * 16 + l16) * 32 + rsw];
#pragma unroll
    for (int ns = 0; ns < 2; ns++)
      bF[ns] = *(const bf16x8*)&sB[(w * 32 + ns * 16 + l16) * 32 + rsw];
#pragma unroll
    for (int ms = 0; ms < 4; ms++)
#pragma unroll
      for (int ns = 0; ns < 2; ns++)
        acc[ms][ns] = MFMA16(aF[ms], bF[ns], acc[ms][ns]);
  }
#pragma unroll
  for (int ms = 0; ms < 4; ms++)
#pragma unroll
    for (int ns = 0; ns < 2; ns++) {
      int rowb = m0 + ms * 16 + quad * 4;          // 4 consecutive s
      int col  = n0 + w * 32 + ns * 16 + l16;
      int bb = rowb >> 10, s = rowb & 1023;
      float bias = bo[col];
      f32x4 vv = acc[ms][ns];
      vv[0] += bias; vv[1] += bias; vv[2] += bias; vv[3] += bias;
      *(f32x4*)&out[((size_t)(bb * NC + col)) * NS + s] = vv;
    }
}

extern "C" void kernel_launch(void* const* d_in, const int* in_sizes, int n_in,
                              void* d_out, int out_size, void* d_ws, size_t ws_size,
                              hipStream_t stream) {
  const float* x  = (const float*)d_in[0];
  const float* gw = (const float*)d_in[1];
  const float* gb = (const float*)d_in[2];
  const float* Wq = (const float*)d_in[3];
  const float* Wk = (const float*)d_in[4];
  const float* Wv = (const float*)d_in[5];
  const float* Wo = (const float*)d_in[6];
  const float* bo = (const float*)d_in[7];
  float* out = (float*)d_out;

  char* ws = (char*)d_ws;
  const size_t MAT = (size_t)8192 * 512 * 2;  // 8 MB bf16
  float* stats = (float*)ws;
  short* xT  = (short*)(ws + 4096);
  short* nT  = (short*)(ws + 4096 + 1 * MAT);
  short* q   = (short*)(ws + 4096 + 2 * MAT);
  short* k   = (short*)(ws + 4096 + 3 * MAT);
  short* vt  = (short*)(ws + 4096 + 4 * MAT);  // V^T [B,H,D,S]
  short* ctx = (short*)(ws + 4096 + 5 * MAT);
  short* wqb = (short*)(ws + 4096 + 6 * MAT);
  short* wkb = wqb + 262144;
  short* wvb = wkb + 262144;
  short* wob = wvb + 262144;

  const float qscale = 0.125f * 1.44269504088896f;  // d^-0.5 * log2(e), folded into Wq
  prep<<<1280, 256, 0, stream>>>(x, stats,
                                 (const float4*)Wq, (const float4*)Wk,
                                 (const float4*)Wv, (const float4*)Wo,
                                 (s16x4*)wqb, (s16x4*)wkb, (s16x4*)wvb, (s16x4*)wob,
                                 qscale);
  tnorm<<<dim3(16, 8, 8), 256, 0, stream>>>(x, stats, gw, gb, xT, nT);
  gemm_qkv<<<dim3(64, 12), 256, 0, stream>>>(nT, xT, wqb, wkb, wvb, q, k, vt);
  attn<<<dim3(64, 8), 512, 0, stream>>>(q, k, vt, ctx);
  gemm_out<<<dim3(128, 4), 256, 0, stream>>>(ctx, wob, bo, out);
}

// Round 10
// 145.240 us; speedup vs baseline: 1.0579x; 1.0284x over previous
//
#include <hip/hip_runtime.h>
#include <hip/hip_bf16.h>

typedef short bf16x8 __attribute__((ext_vector_type(8)));
typedef short s16x4  __attribute__((ext_vector_type(4)));
typedef float f32x4  __attribute__((ext_vector_type(4)));

#define NB 8
#define NC 512
#define NS 1024
#define NH 8
#define DH 64
#define GN_GROUPS 32
#define GN_EPS 1e-5f

#if __has_builtin(__builtin_amdgcn_exp2f)
#define EXP2(x) __builtin_amdgcn_exp2f(x)
#else
#define EXP2(x) __expf((x) * 0.69314718056f)
#endif

static __device__ __forceinline__ short f2bf(float f) {
  union { __hip_bfloat16 h; short s; } u;
  u.h = __float2bfloat16(f);
  return u.s;
}

// round-to-nearest (ties up) bf16 pair pack: 2 adds + 1 v_perm_b32
static __device__ __forceinline__ int pack2bf_fast(float a, float b) {
  unsigned ua = __float_as_uint(a) + 0x8000u;
  unsigned ub = __float_as_uint(b) + 0x8000u;
  return (int)__builtin_amdgcn_perm(ub, ua, 0x07060302u);  // a in low 16 bits
}

static __device__ __forceinline__ void async_lds16(const void* g, void* l) {
  __builtin_amdgcn_global_load_lds((__attribute__((address_space(1))) void*)(g),
                                   (__attribute__((address_space(3))) void*)(l),
                                   16, 0, 0);
}

#define MFMA16(a, b, c) __builtin_amdgcn_mfma_f32_16x16x32_bf16((a), (b), (c), 0, 0, 0)

// ---------------- kernel 1: weight convert + groupnorm stats (one launch) ----------------
__global__ __launch_bounds__(256) void prep(const float* __restrict__ x,
                                            float* __restrict__ stats,
                                            const float4* __restrict__ Wq,
                                            const float4* __restrict__ Wk,
                                            const float4* __restrict__ Wv,
                                            const float4* __restrict__ Wo,
                                            s16x4* __restrict__ oq, s16x4* __restrict__ ok,
                                            s16x4* __restrict__ ov, s16x4* __restrict__ oo,
                                            float qscale) {
  if (blockIdx.x < 256) {  // groupnorm stats: block per (b,g)
    int bg = blockIdx.x;
    const float4* p = (const float4*)(x + (size_t)bg * 16384);
    float s = 0.f, s2 = 0.f;
    for (int i = threadIdx.x; i < 4096; i += 256) {
      float4 v = p[i];
      s  += v.x + v.y + v.z + v.w;
      s2 += v.x * v.x + v.y * v.y + v.z * v.z + v.w * v.w;
    }
    for (int off = 32; off > 0; off >>= 1) {
      s  += __shfl_down(s, off, 64);
      s2 += __shfl_down(s2, off, 64);
    }
    __shared__ float red[8];
    int w = threadIdx.x >> 6;
    if ((threadIdx.x & 63) == 0) { red[w * 2] = s; red[w * 2 + 1] = s2; }
    __syncthreads();
    if (threadIdx.x == 0) {
      float S = 0.f, S2 = 0.f;
      for (int i = 0; i < 4; i++) { S += red[i * 2]; S2 += red[i * 2 + 1]; }
      float mu  = S / 16384.f;
      float var = S2 / 16384.f - mu * mu;
      stats[bg * 2]     = mu;
      stats[bg * 2 + 1] = rsqrtf(var + GN_EPS);
    }
  } else {  // weight fp32 -> bf16
    int idx = blockIdx.x - 256;
    int sel = idx >> 8;
    int i = (idx & 255) * 256 + threadIdx.x;
    const float4* src = (sel == 0) ? Wq : (sel == 1) ? Wk : (sel == 2) ? Wv : Wo;
    s16x4* dst        = (sel == 0) ? oq : (sel == 1) ? ok : (sel == 2) ? ov : oo;
    float scale = (sel == 0) ? qscale : 1.0f;
    float4 f = src[i];
    s16x4 o;
    o[0] = f2bf(f.x * scale); o[1] = f2bf(f.y * scale);
    o[2] = f2bf(f.z * scale); o[3] = f2bf(f.w * scale);
    dst[i] = o;
  }
}

// ---------------- kernel 2: transpose + groupnorm apply ----------------
__global__ __launch_bounds__(256) void tnorm(const float* __restrict__ x,
                                             const float* __restrict__ stats,
                                             const float* __restrict__ gw,
                                             const float* __restrict__ gb,
                                             short* __restrict__ xT,
                                             short* __restrict__ nT) {
  __shared__ float tile[64 * 65];
  int b = blockIdx.z, c0 = blockIdx.y * 64, s0 = blockIdx.x * 64;
  int t = threadIdx.x;
  const float* xp = x + ((size_t)b * NC + c0) * NS + s0;
#pragma unroll
  for (int p = 0; p < 4; p++) {
    int idx = p * 256 + t;
    int cl = idx >> 4;
    int s4 = (idx & 15) * 4;
    float4 v = *(const float4*)(xp + (size_t)cl * NS + s4);
    tile[cl * 65 + s4 + 0] = v.x;
    tile[cl * 65 + s4 + 1] = v.y;
    tile[cl * 65 + s4 + 2] = v.z;
    tile[cl * 65 + s4 + 3] = v.w;
  }
  __syncthreads();
#pragma unroll
  for (int p = 0; p < 4; p++) {
    int idx = p * 256 + t;
    int sl = idx >> 4;
    int c4 = (idx & 15) * 4;
    size_t ob = ((size_t)b * NS + s0 + sl) * NC + c0 + c4;
    s16x4 xo, no;
#pragma unroll
    for (int j = 0; j < 4; j++) {
      int c = c0 + c4 + j;
      float val = tile[(c4 + j) * 65 + sl];
      int g = c >> 4;
      float mu = stats[(b * GN_GROUPS + g) * 2];
      float rs = stats[(b * GN_GROUPS + g) * 2 + 1];
      float nv = (val - mu) * rs * gw[c] + gb[c];
      xo[j] = f2bf(val);
      no[j] = f2bf(nv);
    }
    *(s16x4*)(xT + ob) = xo;
    *(s16x4*)(nT + ob) = no;
  }
}

// ---------------- kernel 3: fused q/k/v GEMM (BK=32, XOR swizzle, vectorized epilogue) ----------------
__global__ __launch_bounds__(256) void gemm_qkv(const short* __restrict__ nT,
                                                const short* __restrict__ xT,
                                                const short* __restrict__ wq,
                                                const short* __restrict__ wk,
                                                const short* __restrict__ wv,
                                                short* __restrict__ q,
                                                short* __restrict__ k,
                                                short* __restrict__ vt) {
  __shared__ __attribute__((aligned(16))) short smem[8704];  // panels 2x4096; epilogue 64x136
  short* sA = smem;
  short* sB = smem + 4096;
  int proj = blockIdx.y >> 2;
  int n0 = (blockIdx.y & 3) * 128;
  int m0 = blockIdx.x * 128;
  const short* A  = (proj == 0) ? nT : xT;
  const short* Bm = (proj == 0) ? wq : ((proj == 1) ? wk : wv);
  short* Out      = (proj == 0) ? q  : ((proj == 1) ? k  : vt);

  int tid = threadIdx.x, lane = tid & 63, w = tid >> 6;
  int quad = lane >> 4, l16 = lane & 15;
  int m_off = (w >> 1) * 64, n_off = (w & 1) * 64;
  int sr4 = lane >> 2;
  int csw = ((lane & 3) ^ ((sr4 >> 1) & 3)) * 8;
  int rsw = (quad ^ ((l16 >> 1) & 3)) * 8;

  const short* gA = A  + ((size_t)(m0 + w * 32 + sr4)) * 512 + csw;
  const short* gB = Bm + ((size_t)(n0 + w * 32 + sr4)) * 512 + csw;
  short* lA = &sA[w * 1024];
  short* lB = &sB[w * 1024];

  f32x4 acc[4][4] = {};

  for (int kk = 0; kk < 512; kk += 32) {
    __syncthreads();
    async_lds16(gA + kk,            lA);
    async_lds16(gA + kk + 16 * 512, lA + 512);
    async_lds16(gB + kk,            lB);
    async_lds16(gB + kk + 16 * 512, lB + 512);
    __syncthreads();
    bf16x8 aF[4], bF[4];
#pragma unroll
    for (int ms = 0; ms < 4; ms++)
      aF[ms] = *(const bf16x8*)&sA[(m_off + ms * 16 + l16) * 32 + rsw];
#pragma unroll
    for (int ns = 0; ns < 4; ns++)
      bF[ns] = *(const bf16x8*)&sB[(n_off + ns * 16 + l16) * 32 + rsw];
#pragma unroll
    for (int ms = 0; ms < 4; ms++)
#pragma unroll
      for (int ns = 0; ns < 4; ns++)
        acc[ms][ns] = MFMA16(aF[ms], bF[ns], acc[ms][ns]);
  }
  if (proj < 2) {
    // LDS-transpose epilogue: two 64-row halves, dwordx4 global stores
    short* sT = smem;  // 64 x 136 (272 B rows: 16B-aligned, bank-rotated)
    int hown = m_off >> 6;
#pragma unroll
    for (int hm = 0; hm < 2; hm++) {
      __syncthreads();
      if (hown == hm) {
#pragma unroll
        for (int ms = 0; ms < 4; ms++)
#pragma unroll
          for (int ns = 0; ns < 4; ns++)
#pragma unroll
            for (int r = 0; r < 4; r++)
              sT[(ms * 16 + quad * 4 + r) * 136 + n_off + ns * 16 + l16] = f2bf(acc[ms][ns][r]);
      }
      __syncthreads();
#pragma unroll
      for (int p2 = 0; p2 < 4; p2++) {
        int idx = p2 * 256 + tid;
        int row = idx >> 4, ch = (idx & 15) * 8;
        *(bf16x8*)&Out[(size_t)(m0 + hm * 64 + row) * 512 + n0 + ch] =
            *(const bf16x8*)&sT[row * 136 + ch];
      }
    }
  } else {
    // transposed store: vT[b, h=col>>6, d=col&63, s] ; 4 consecutive s per lane
#pragma unroll
    for (int ms = 0; ms < 4; ms++)
#pragma unroll
      for (int ns = 0; ns < 4; ns++) {
        int rowb = m0 + m_off + ms * 16 + quad * 4;  // s base (4 consecutive)
        int col  = n0 + n_off + ns * 16 + l16;       // channel
        int bb = rowb >> 10, s = rowb & 1023;
        s16x4 pk4;
#pragma unroll
        for (int r = 0; r < 4; r++) pk4[r] = f2bf(acc[ms][ns][r]);
        *(s16x4*)&Out[((size_t)(bb * NC + col)) * NS + s] = pk4;
      }
  }
}

// ---------------- kernel 4: flash attention, split-KV in-block, LDS P-relayout ----------------
// grid (64 b*h, 8 q-tiles of 128); block 512 = 8 waves; 32-kv iterations.
// Wave-group wg handles kv [wg*512, wg*512+512); P^T relayout via intra-wave LDS
// (lane writes its q-rows, reads its q-rows: no barrier, lgkmcnt only).
__global__ __launch_bounds__(512, 4) void attn(const short* __restrict__ q,
                                               const short* __restrict__ k,
                                               const short* __restrict__ vT,
                                               short* __restrict__ ctx) {
  // SK: 8 half-panels [32 kv x 32 d'] (16 KB) | SV: 4 panels [64 d x 32 kv] (16 KB)
  // P: 8 waves x [32 q x 40 shorts] (20 KB)   => 52 KB total
  __shared__ __attribute__((aligned(16))) short smem[26624];
#define SKh(wg, p, hf) (&smem[((wg) * 4 + (p) * 2 + (hf)) * 1024])
#define SVp(wg, p)     (&smem[8192 + ((wg) * 2 + (p)) * 2048])
  int b = blockIdx.x >> 3, h = blockIdx.x & 7;
  int q0 = blockIdx.y * 128;
  int tid = threadIdx.x, lane = tid & 63, w = tid >> 6;
  int wg = w >> 2, wl = w & 3;
  int quad = lane >> 4, l16 = lane & 15;

  const short* kb = k  + (size_t)b * (NS * NC) + h * DH;
  const short* vb = vT + (size_t)(b * NH + h) * (DH * NS);
  short* pw = &smem[16384 + w * 1280];  // per-wave P scratch

  // Q B-frags (persistent): B[n=q(l16)][k=d(hf*32+quad*8+j)]
  bf16x8 qf[2][2];
#pragma unroll
  for (int g = 0; g < 2; g++) {
    const short* qp = q + ((size_t)(b * NS + q0 + g * 64 + wl * 16 + l16)) * NC + h * DH + quad * 8;
    qf[g][0] = *(const bf16x8*)qp;
    qf[g][1] = *(const bf16x8*)(qp + 32);
  }

#define STAGE(p, kt) do {                                                  \
    int kv0_ = wg * 512 + (kt) * 32;                                       \
    int kr_ = (wl >> 1) * 16 + (lane >> 2);                                \
    int kc_ = (wl & 1) * 32 + (((lane & 3) ^ ((kr_ >> 1) & 3)) * 8);       \
    async_lds16(kb + (size_t)(kv0_ + kr_) * NC + kc_,                      \
                SKh(wg, p, wl & 1) + (wl >> 1) * 512);                     \
    int vr_ = wl * 16 + (lane >> 2);                                       \
    int vc_ = ((lane & 3) ^ ((vr_ >> 1) & 3)) * 8;                         \
    async_lds16(vb + (size_t)vr_ * NS + kv0_ + vc_,                        \
                SVp(wg, p) + wl * 512);                                    \
  } while (0)

  STAGE(0, 0);

  f32x4 o[2][4] = {};
  float lsum[2] = {0.f, 0.f};

  for (int kt = 0; kt < 16; kt++) {
    int p = kt & 1;
    __syncthreads();
    if (kt < 15) STAGE(1 - p, kt + 1);

    // S^T tiles: sc[g][mt], row=kv(mt*16+quad*4+r), col=q(l16)
    f32x4 sc[2][2];
#pragma unroll
    for (int mt = 0; mt < 2; mt++) {
      int row = mt * 16 + l16;
      int fro = row * 32 + ((quad ^ ((row >> 1) & 3)) * 8);
      bf16x8 ak0 = *(const bf16x8*)(SKh(wg, p, 0) + fro);
      bf16x8 ak1 = *(const bf16x8*)(SKh(wg, p, 1) + fro);
#pragma unroll
      for (int g = 0; g < 2; g++) {
        f32x4 z = {0.f, 0.f, 0.f, 0.f};
        z = MFMA16(ak0, qf[g][0], z);
        z = MFMA16(ak1, qf[g][1], z);
        sc[g][mt] = z;
      }
    }
    // exp2 + pack + intra-wave P write: row qi = g*16+l16 (the lane's own q),
    // cols kv = mt*16 + quad*4 + {0..3} as one b64
#pragma unroll
    for (int g = 0; g < 2; g++) {
      int qi = (g * 16 + l16) * 40;
#pragma unroll
      for (int mt = 0; mt < 2; mt++) {
        float e0 = EXP2(sc[g][mt][0]);
        float e1 = EXP2(sc[g][mt][1]);
        float e2 = EXP2(sc[g][mt][2]);
        float e3 = EXP2(sc[g][mt][3]);
        lsum[g] += (e0 + e1) + (e2 + e3);
        int2 pr;
        pr.x = pack2bf_fast(e0, e1);
        pr.y = pack2bf_fast(e2, e3);
        *(int2*)&pw[qi + mt * 16 + quad * 4] = pr;
      }
    }
    __builtin_amdgcn_s_waitcnt(0xc07f);  // lgkmcnt(0) only — vmcnt (prefetch) untouched
    // P^T B-frags: row n=q(l16), k=kv(quad*8+j) — reads the rows this wave wrote
    bf16x8 pf[2];
#pragma unroll
    for (int g = 0; g < 2; g++)
      pf[g] = *(const bf16x8*)&pw[(g * 16 + l16) * 40 + quad * 8];
    // O^T += V^T P^T
#pragma unroll
    for (int dt = 0; dt < 4; dt++) {
      int row = dt * 16 + l16;
      bf16x8 av = *(const bf16x8*)(SVp(wg, p) + row * 32 + ((quad ^ ((row >> 1) & 3)) * 8));
#pragma unroll
      for (int g = 0; g < 2; g++)
        o[g][dt] = MFMA16(av, pf[g], o[g][dt]);
    }
  }
  // per-wave quad reduction of denominator
#pragma unroll
  for (int g = 0; g < 2; g++) {
    lsum[g] += __shfl_xor(lsum[g], 16, 64);
    lsum[g] += __shfl_xor(lsum[g], 32, 64);
  }
  // cross-group combine (panels + P dead after this barrier)
  float* dump  = (float*)smem;            // 32 KB
  float* lsums = (float*)&smem[16384];    // 512 B (P region)
  __syncthreads();
  if (wg == 1) {
#pragma unroll
    for (int g = 0; g < 2; g++) {
#pragma unroll
      for (int dt = 0; dt < 4; dt++)
        *(f32x4*)&dump[((((g * 4 + wl) * 4) + dt) * 64 + lane) * 4] = o[g][dt];
      if (quad == 0) lsums[(g * 4 + wl) * 16 + l16] = lsum[g];
    }
  }
  __syncthreads();
  float inv[2];
  if (wg == 0) {
#pragma unroll
    for (int g = 0; g < 2; g++) {
      inv[g] = 1.f / (lsum[g] + lsums[(g * 4 + wl) * 16 + l16]);
#pragma unroll
      for (int dt = 0; dt < 4; dt++) {
        f32x4 add = *(const f32x4*)&dump[((((g * 4 + wl) * 4) + dt) * 64 + lane) * 4];
        o[g][dt] += add;
      }
    }
  }
  __syncthreads();
  // epilogue: O^T (row=d, col=q) -> LDS transpose -> coalesced ctx [B,S,C]
  short* sT = &smem[0];  // 128 q-rows x 72 (18 KB)
  if (wg == 0) {
#pragma unroll
    for (int g = 0; g < 2; g++)
#pragma unroll
      for (int dt = 0; dt < 4; dt++)
#pragma unroll
        for (int r = 0; r < 4; r++)
          sT[(g * 64 + wl * 16 + l16) * 72 + dt * 16 + quad * 4 + r] = f2bf(o[g][dt][r] * inv[g]);
  }
  __syncthreads();
  for (int it = tid; it < 1024; it += 512) {
    int row = it >> 3, ch = (it & 7) * 8;
    *(bf16x8*)&ctx[((size_t)(b * NS + q0 + row)) * NC + h * DH + ch] =
        *(const bf16x8*)&sT[row * 72 + ch];
  }
#undef STAGE
#undef SKh
#undef SVp
}

// ---------------- kernel 5: out = ctx @ Wo^T + bo, 64x128 tiles, f32x4 stores ----------------
__global__ __launch_bounds__(256) void gemm_out(const short* __restrict__ ctx,
                                                const short* __restrict__ wo,
                                                const float* __restrict__ bo,
                                                float* __restrict__ out) {
  __shared__ __attribute__((aligned(16))) short sA[64 * 32];
  __shared__ __attribute__((aligned(16))) short sB[128 * 32];
  int n0 = blockIdx.y * 128;
  int m0 = blockIdx.x * 64;
  int tid = threadIdx.x, lane = tid & 63, w = tid >> 6;
  int quad = lane >> 4, l16 = lane & 15;
  int sr4 = lane >> 2;
  int csw = ((lane & 3) ^ ((sr4 >> 1) & 3)) * 8;
  int rsw = (quad ^ ((l16 >> 1) & 3)) * 8;

  const short* gA = ctx + ((size_t)(m0 + w * 16 + sr4)) * 512 + csw;
  const short* gB = wo  + ((size_t)(n0 + w * 32 + sr4)) * 512 + csw;
  short* lA = &sA[w * 512];
  short* lB = &sB[w * 1024];

  f32x4 acc[4][2] = {};

  for (int kk = 0; kk < 512; kk += 32) {
    __syncthreads();
    async_lds16(gA + kk,            lA);
    async_lds16(gB + kk,            lB);
    async_lds16(gB + kk + 16 * 512, lB + 512);
    __syncthreads();
    bf16x8 aF[4], bF[2];
#pragma unroll
    for (int ms = 0; ms < 4; ms++)
      aF[ms] = *(const bf16x8*)&sA[(ms * 16 + l16) * 32 + rsw];
#pragma unroll
    for (int ns = 0; ns < 2; ns++)
      bF[ns] = *(const bf16x8*)&sB[(w * 32 + ns * 16 + l16) * 32 + rsw];
#pragma unroll
    for (int ms = 0; ms < 4; ms++)
#pragma unroll
      for (int ns = 0; ns < 2; ns++)
        acc[ms][ns] = MFMA16(aF[ms], bF[ns], acc[ms][ns]);
  }
#pragma unroll
  for (int ms = 0; ms < 4; ms++)
#pragma unroll
    for (int ns = 0; ns < 2; ns++) {
      int rowb = m0 + ms * 16 + quad * 4;          // 4 consecutive s
      int col  = n0 + w * 32 + ns * 16 + l16;
      int bb = rowb >> 10, s = rowb & 1023;
      float bias = bo[col];
      f32x4 vv = acc[ms][ns];
      vv[0] += bias; vv[1] += bias; vv[2] += bias; vv[3] += bias;
      *(f32x4*)&out[((size_t)(bb * NC + col)) * NS + s] = vv;
    }
}

extern "C" void kernel_launch(void* const* d_in, const int* in_sizes, int n_in,
                              void* d_out, int out_size, void* d_ws, size_t ws_size,
                              hipStream_t stream) {
  const float* x  = (const float*)d_in[0];
  const float* gw = (const float*)d_in[1];
  const float* gb = (const float*)d_in[2];
  const float* Wq = (const float*)d_in[3];
  const float* Wk = (const float*)d_in[4];
  const float* Wv = (const float*)d_in[5];
  const float* Wo = (const float*)d_in[6];
  const float* bo = (const float*)d_in[7];
  float* out = (float*)d_out;

  char* ws = (char*)d_ws;
  const size_t MAT = (size_t)8192 * 512 * 2;  // 8 MB bf16
  float* stats = (float*)ws;
  short* xT  = (short*)(ws + 4096);
  short* nT  = (short*)(ws + 4096 + 1 * MAT);
  short* q   = (short*)(ws + 4096 + 2 * MAT);
  short* k   = (short*)(ws + 4096 + 3 * MAT);
  short* vt  = (short*)(ws + 4096 + 4 * MAT);  // V^T [B,H,D,S]
  short* ctx = (short*)(ws + 4096 + 5 * MAT);
  short* wqb = (short*)(ws + 4096 + 6 * MAT);
  short* wkb = wqb + 262144;
  short* wvb = wkb + 262144;
  short* wob = wvb + 262144;

  const float qscale = 0.125f * 1.44269504088896f;  // d^-0.5 * log2(e), folded into Wq
  prep<<<1280, 256, 0, stream>>>(x, stats,
                                 (const float4*)Wq, (const float4*)Wk,
                                 (const float4*)Wv, (const float4*)Wo,
                                 (s16x4*)wqb, (s16x4*)wkb, (s16x4*)wvb, (s16x4*)wob,
                                 qscale);
  tnorm<<<dim3(16, 8, 8), 256, 0, stream>>>(x, stats, gw, gb, xT, nT);
  gemm_qkv<<<dim3(64, 12), 256, 0, stream>>>(nT, xT, wqb, wkb, wvb, q, k, vt);
  attn<<<dim3(64, 8), 512, 0, stream>>>(q, k, vt, ctx);
  gemm_out<<<dim3(128, 4), 256, 0, stream>>>(ctx, wob, bo, out);
}